// Round 11
// baseline (308.559 us; speedup 1.0000x reference)
//
#include <hip/hip_runtime.h>

typedef __bf16 bf16x8 __attribute__((ext_vector_type(8)));
typedef __bf16 bf16x4 __attribute__((ext_vector_type(4)));
typedef float f32x4 __attribute__((ext_vector_type(4)));
typedef unsigned u32x2 __attribute__((ext_vector_type(2)));
typedef unsigned u32x4 __attribute__((ext_vector_type(4)));

// async global->LDS direct copy, 16 B per lane (wave-uniform LDS base + lane*16)
typedef const __attribute__((address_space(1))) void* as1_cvp;
typedef __attribute__((address_space(3))) void* as3_vp;
__device__ __forceinline__ void g2l16(const void* g, void* l) {
  __builtin_amdgcn_global_load_lds((as1_cvp)(uintptr_t)g, (as3_vp)(uintptr_t)l, 16, 0, 0);
}

// pack two f32 -> one u32 of two bf16
__device__ __forceinline__ unsigned pk2(float lo, float hi) {
  unsigned short l = __builtin_bit_cast(unsigned short, (__bf16)lo);
  unsigned short h = __builtin_bit_cast(unsigned short, (__bf16)hi);
  return (unsigned)l | ((unsigned)h << 16);
}

// ---------------- fused casts ----------------
__global__ __launch_bounds__(256) void cast_all(const float* __restrict__ q,
                                                const float* __restrict__ wq,
                                                const float* __restrict__ wk,
                                                const float* __restrict__ wv,
                                                const float* __restrict__ wo,
                                                __bf16* __restrict__ xb,
                                                __bf16* __restrict__ wqkv,
                                                __bf16* __restrict__ wob, float qs) {
  const int y = blockIdx.y;
  const float* src;
  __bf16* dst;
  int n4;
  float s = 1.0f;
  if (y == 0) {
    src = q; dst = xb; n4 = 1048576;
  } else if (y == 1) {
    src = wq; dst = wqkv; n4 = 262144; s = qs;
  } else if (y == 2) {
    src = wk; dst = wqkv + 1048576; n4 = 262144;
  } else if (y == 3) {
    src = wv; dst = wqkv + 2097152; n4 = 262144;
  } else {
    src = wo; dst = wob; n4 = 262144;
  }
  for (int idx = blockIdx.x * 256 + threadIdx.x; idx < n4; idx += gridDim.x * 256) {
    float4 f = reinterpret_cast<const float4*>(src)[idx];
    bf16x4 t;
    t.x = (__bf16)(f.x * s); t.y = (__bf16)(f.y * s);
    t.z = (__bf16)(f.z * s); t.w = (__bf16)(f.w * s);
    reinterpret_cast<bf16x4*>(dst)[idx] = t;
  }
}

// ---------------- QKV GEMM: 256x256, 8-phase counted-vmcnt (R10, passing) ----------------
__global__ __launch_bounds__(512, 2) void gemm8p(const __bf16* __restrict__ A,
                                                 const __bf16* __restrict__ B,
                                                 const float* __restrict__ b0,
                                                 const float* __restrict__ b1,
                                                 const float* __restrict__ b2,
                                                 __bf16* __restrict__ C,
                                                 __bf16* __restrict__ Vt,
                                                 int K, int ldc, float qs) {
  __shared__ __align__(16) __bf16 Alds[2][256][64];  // 64 KiB
  __shared__ __align__(16) __bf16 Blds[2][256][64];  // 64 KiB
  const int tid = threadIdx.x;
  const int wave = tid >> 6, lane = tid & 63;
  const int wm = wave >> 2, wn = wave & 3;
  const int mlane = lane & 15, quad = lane >> 4;
  const int m7 = mlane & 7;
  const int nwg = (int)(gridDim.x * gridDim.y);
  const int lin = (int)(blockIdx.y * gridDim.x + blockIdx.x);
  const int sl = (lin & 7) * (nwg >> 3) + (lin >> 3);
  const int bx = sl % (int)gridDim.x, by = sl / (int)gridDim.x;
  const int m0 = bx * 256, n0 = by * 256;

  f32x4 acc[8][4] = {};

  size_t aoff[2], boff[2];
  int ldso[2];
#pragma unroll
  for (int j = 0; j < 2; j++) {
    int c = j * 512 + tid, r = c >> 3, slo = c & 7;
    aoff[j] = ((size_t)(m0 + r) * K + (size_t)((slo ^ (r & 7)) * 8)) * 2;
    boff[j] = ((size_t)(n0 + r) * K + (size_t)((slo ^ (r & 7)) * 8)) * 2;
    ldso[j] = c * 16;
  }
  const char* Ag = (const char*)A;
  const char* Bg = (const char*)B;
  char* Ad = (char*)&Alds[0][0][0];
  char* Bd = (char*)&Blds[0][0][0];
  const size_t ghalf = (size_t)128 * K * 2;

  auto stA = [&](int t, int h) {
#pragma unroll
    for (int j = 0; j < 2; j++)
      g2l16(Ag + aoff[j] + (size_t)h * ghalf + (size_t)t * 128,
            Ad + ((t & 1) << 15) + (h << 14) + ldso[j]);
  };
  auto stB = [&](int t, int h) {
#pragma unroll
    for (int j = 0; j < 2; j++)
      g2l16(Bg + boff[j] + (size_t)h * ghalf + (size_t)t * 128,
            Bd + ((t & 1) << 15) + (h << 14) + ldso[j]);
  };

  auto bar = [] {
    asm volatile("" ::: "memory");
    __builtin_amdgcn_s_barrier();
    asm volatile("" ::: "memory");
  };

  bf16x8 af[4][2], bfrL[2][2], bfrH[2][2];
  auto ldA = [&](int buf, int mh) {
#pragma unroll
    for (int mt = 0; mt < 4; mt++)
#pragma unroll
      for (int s = 0; s < 2; s++)
        af[mt][s] = *reinterpret_cast<const bf16x8*>(
            &Alds[buf][mh * 128 + wm * 64 + mt * 16 + mlane][((4 * s + quad) ^ m7) * 8]);
  };
  auto ldB = [&](int buf, int nh, bf16x8 (&bf)[2][2]) {
#pragma unroll
    for (int nt = 0; nt < 2; nt++)
#pragma unroll
      for (int s = 0; s < 2; s++)
        bf[nt][s] = *reinterpret_cast<const bf16x8*>(
            &Blds[buf][nh * 128 + wn * 32 + nt * 16 + mlane][((4 * s + quad) ^ m7) * 8]);
  };
  auto mma = [&](int mh, int nh, bf16x8 (&bf)[2][2]) {
    __builtin_amdgcn_s_setprio(1);
#pragma unroll
    for (int mt = 0; mt < 4; mt++)
#pragma unroll
      for (int nt = 0; nt < 2; nt++)
#pragma unroll
        for (int s = 0; s < 2; s++)
          acc[mh * 4 + mt][nh * 2 + nt] = __builtin_amdgcn_mfma_f32_16x16x32_bf16(
              af[mt][s], bf[nt][s], acc[mh * 4 + mt][nh * 2 + nt], 0, 0, 0);
    __builtin_amdgcn_s_setprio(0);
  };

  const int nk = K >> 6;
  const int nit = nk >> 1;

  stA(0, 0); stB(0, 0); stA(0, 1); stB(0, 1); stA(1, 0); stB(1, 0);
  asm volatile("s_waitcnt vmcnt(8)" ::: "memory");
  bar();

  for (int i = 0; i < nit; ++i) {
    const int t1 = 2 * i + 1, t2 = 2 * i + 2, t3 = 2 * i + 3;
    const bool last = (i == nit - 1);
    ldA(0, 0); ldB(0, 0, bfrL);
    stA(t1, 1); stB(t1, 1);
    asm volatile("s_waitcnt vmcnt(8)" ::: "memory");
    bar(); mma(0, 0, bfrL); bar();
    ldB(0, 1, bfrH);
    bar(); mma(0, 1, bfrH); bar();
    ldA(0, 1);
    if (t2 < nk) stA(t2, 0);
    bar(); mma(1, 0, bfrL); bar();
    if (t2 < nk) stB(t2, 0);
    if (last) { asm volatile("s_waitcnt vmcnt(4)" ::: "memory"); }
    else      { asm volatile("s_waitcnt vmcnt(8)" ::: "memory"); }
    bar(); mma(1, 1, bfrH); bar();
    ldA(1, 0); ldB(1, 0, bfrL);
    if (t2 < nk) { stA(t2, 1); stB(t2, 1); }
    if (last) { asm volatile("s_waitcnt vmcnt(0)" ::: "memory"); }
    else      { asm volatile("s_waitcnt vmcnt(8)" ::: "memory"); }
    bar(); mma(0, 0, bfrL); bar();
    ldB(1, 1, bfrH);
    bar(); mma(0, 1, bfrH); bar();
    ldA(1, 1);
    if (t3 < nk) stA(t3, 0);
    bar(); mma(1, 0, bfrL); bar();
    if (t3 < nk) stB(t3, 0);
    if (!last) { asm volatile("s_waitcnt vmcnt(8)" ::: "memory"); }
    bar(); mma(1, 1, bfrH); bar();
  }

  const int region = n0 >> 10;
  const float* bp = region == 0 ? b0 : (region == 1 ? b1 : b2);
  const float bs = (region == 0) ? qs : 1.0f;
  float bvs[4];
#pragma unroll
  for (int ni = 0; ni < 4; ni++) {
    int nh = ni >> 1, nt = ni & 1;
    bvs[ni] = bp[(n0 + nh * 128 + wn * 32 + nt * 16 + mlane) & 1023] * bs;
  }

  if (region == 2) {
#pragma unroll
    for (int mi = 0; mi < 8; mi++) {
      int mh = mi >> 2, mt = mi & 3;
      int row0 = m0 + mh * 128 + wm * 64 + mt * 16 + quad * 4;
#pragma unroll
      for (int ni = 0; ni < 4; ni++) {
        int nh = ni >> 1, nt = ni & 1;
        int vcol = (n0 + nh * 128 + wn * 32 + nt * 16 + mlane) & 1023;
        bf16x4 t;
#pragma unroll
        for (int r = 0; r < 4; r++) t[r] = (__bf16)(acc[mi][ni][r] + bvs[ni]);
        *reinterpret_cast<bf16x4*>(&Vt[(size_t)vcol * 4096 + row0]) = t;
      }
    }
  } else {
#pragma unroll
    for (int mi = 0; mi < 8; mi++) {
      int mh = mi >> 2, mt = mi & 3;
#pragma unroll
      for (int ni = 0; ni < 4; ni++) {
        int nh = ni >> 1, nt = ni & 1;
        int col = n0 + nh * 128 + wn * 32 + nt * 16 + mlane;
#pragma unroll
        for (int r = 0; r < 4; r++) {
          int row = m0 + mh * 128 + wm * 64 + mt * 16 + quad * 4 + r;
          C[(size_t)row * ldc + col] = (__bf16)(acc[mi][ni][r] + bvs[ni]);
        }
      }
    }
  }
}

// ---------------- output-projection GEMM (R8 structure, passing) ----------------
template <int BM, typename OUT_T>
__global__ __launch_bounds__(512, 4) void gemm_bt(const __bf16* __restrict__ A,
                                                  const __bf16* __restrict__ B,
                                                  const float* __restrict__ b0,
                                                  OUT_T* __restrict__ C,
                                                  int K, int ldc) {
  constexpr int MT = BM / 32;
  constexpr int AN = BM / 64;
  __shared__ __align__(16) __bf16 Alds[2][BM][64];
  __shared__ __align__(16) __bf16 Blds[2][128][64];
  const int tid = threadIdx.x;
  const int wave = tid >> 6, lane = tid & 63;
  const int wm = wave >> 2, wn = wave & 3;
  const int mlane = lane & 15, quad = lane >> 4;
  const int m7 = mlane & 7;
  const int nwg = (int)(gridDim.x * gridDim.y);
  const int lin = (int)(blockIdx.y * gridDim.x + blockIdx.x);
  const int sl = (lin & 7) * (nwg >> 3) + (lin >> 3);
  const int bx = sl % (int)gridDim.x, by = sl / (int)gridDim.x;
  const int m0 = bx * BM, n0 = by * 128;

  f32x4 acc[MT][2] = {};

  auto STAGE = [&](int k0, int buf) {
#pragma unroll
    for (int j = 0; j < AN; j++) {
      int c = j * 512 + tid;
      int r = c >> 3, slo = c & 7;
      g2l16(&A[(size_t)(m0 + r) * K + k0 + ((slo ^ (r & 7)) * 8)],
            &Alds[buf][0][0] + c * 8);
    }
#pragma unroll
    for (int j = 0; j < 2; j++) {
      int c = j * 512 + tid;
      int r = c >> 3, slo = c & 7;
      g2l16(&B[(size_t)(n0 + r) * K + k0 + ((slo ^ (r & 7)) * 8)],
            &Blds[buf][0][0] + c * 8);
    }
  };

  STAGE(0, 0);
  __syncthreads();
  const int nk = K >> 6;
  for (int t = 0; t < nk; ++t) {
    const int buf = t & 1;
    if (t + 1 < nk) STAGE((t + 1) << 6, buf ^ 1);
    bf16x8 af[MT][2], bfr[2][2];
#pragma unroll
    for (int mt = 0; mt < MT; mt++)
#pragma unroll
      for (int s = 0; s < 2; s++)
        af[mt][s] = *reinterpret_cast<const bf16x8*>(
            &Alds[buf][wm * (BM / 2) + mt * 16 + mlane][((4 * s + quad) ^ m7) * 8]);
#pragma unroll
    for (int nt = 0; nt < 2; nt++)
#pragma unroll
      for (int s = 0; s < 2; s++)
        bfr[nt][s] = *reinterpret_cast<const bf16x8*>(
            &Blds[buf][wn * 32 + nt * 16 + mlane][((4 * s + quad) ^ m7) * 8]);
#pragma unroll
    for (int mt = 0; mt < MT; mt++)
#pragma unroll
      for (int nt = 0; nt < 2; nt++)
#pragma unroll
        for (int s = 0; s < 2; s++)
          acc[mt][nt] = __builtin_amdgcn_mfma_f32_16x16x32_bf16(af[mt][s], bfr[nt][s],
                                                                acc[mt][nt], 0, 0, 0);
    __syncthreads();
  }

  float bvs[2];
#pragma unroll
  for (int nt = 0; nt < 2; nt++)
    bvs[nt] = b0[(n0 + wn * 32 + nt * 16 + mlane) & 1023];

#pragma unroll
  for (int mt = 0; mt < MT; mt++)
#pragma unroll
    for (int nt = 0; nt < 2; nt++) {
      int col = n0 + wn * 32 + nt * 16 + mlane;
#pragma unroll
      for (int r = 0; r < 4; r++) {
        int row = m0 + wm * (BM / 2) + mt * 16 + quad * 4 + r;
        C[(size_t)row * ldc + col] = (OUT_T)(acc[mt][nt][r] + bvs[nt]);
      }
    }
}

// ---------------- causal flash attention ----------------
// R11 changes:
//  - V fragments read DIRECTLY from global (L2-resident per-XCD since R6's swizzle;
//    FETCH=12MB proves it). Removes V staging + Vlds: -48KB/block-tile of LDS
//    traffic (~30% of the dominant LDS pipe). vf loads issued right after QK^T so
//    ~200cyc L2 latency hides under softmax+pack; per-(s,nt) access = 16 rows x
//    64B contiguous segments; 4 waves/half re-read the same 8KB -> L1 serves.
//  - skip fully-masked half-tiles (wave-uniform: kb*128+half*64 > qbase+15) --
//    every even-qb pass had half-1 burning a whole dead tile (~3% of work).
//  - LDS 65536 -> 32768 (K dbuf only; merge scratch overlays it).
__global__ __launch_bounds__(512, 4) void flash_attn(const __bf16* __restrict__ QK,
                                                     const __bf16* __restrict__ Vt,
                                                     __bf16* __restrict__ O, int S) {
  const int LDQ = 2048, D = 1024;
  __shared__ __align__(16) char smem[32768];  // K0 @0, K1 @16384
  const int tid = threadIdx.x;
  const int wave = tid >> 6, lane = tid & 63;
  const int mlane = lane & 15, quad = lane >> 4;
  const int half = wave >> 2, rw = wave & 3;
  const int lin = (int)(blockIdx.y * 32 + blockIdx.x);
  const int sl = (lin & 7) * 64 + (lin >> 3);
  const int b = sl & 31, h = sl >> 5;
  const int m7 = mlane & 7;

  // hoisted K staging bases (tile-invariant)
  const __bf16* kgb[2];
  int kds[2];
#pragma unroll
  for (int j = 0; j < 2; j++) {
    int c = j * 512 + tid;
    int r = c >> 3, sl2 = c & 7;
    kgb[j] = QK + (size_t)r * LDQ + 1024 + h * 64 + ((sl2 ^ (r & 7)) * 8);
    kds[j] = c * 16;
  }
  // hoisted per-lane V base: row (h*64 + mlane), col offset half*64 + quad*8
  const __bf16* vb = Vt + (size_t)(h * 64 + mlane) * S + half * 64 + quad * 8;

  for (int pass = 0; pass < 2; ++pass) {
    const int qb = pass ? b : (63 - b);
    const int qbase = qb * 64 + rw * 16;
    const int qg = qbase + mlane;

    bf16x8 qf[2];
#pragma unroll
    for (int s = 0; s < 2; s++)
      qf[s] = *reinterpret_cast<const bf16x8*>(
          &QK[(size_t)(qbase + mlane) * LDQ + h * 64 + s * 32 + quad * 8]);

    f32x4 o[4] = {};
    float lsum = 0.f;

    const int nkb = qb / 2 + 1;

    auto STAGEK = [&](int t, int buf) {
      char* kd = smem + buf * 16384;
      const size_t ko = (size_t)t * 128 * LDQ;
#pragma unroll
      for (int j = 0; j < 2; j++) g2l16(kgb[j] + ko, kd + kds[j]);
    };

    STAGEK(0, 0);
    __syncthreads();

    for (int kb = 0; kb < nkb; ++kb) {
      const int buf = kb & 1;
      __bf16(*Klds)[64] = (__bf16(*)[64])(smem + buf * 16384);

      if (kb + 1 < nkb) STAGEK(kb + 1, buf ^ 1);

      // wave-uniform dead-tile skip: lowest key of this wave's half-tile vs the
      // wave's max q-row (qbase+15). exp2(-inf)=0 contributions anyway.
      const bool dead = (kb * 128 + half * 64) > (qbase + 15);
      if (!dead) {
        // S^T = K Q^T (swapped): lane (quad,mlane) holds S^T[key=nt*16+quad*4+r][q=mlane]
        f32x4 sc[4];
        __builtin_amdgcn_s_setprio(1);
#pragma unroll
        for (int nt = 0; nt < 4; nt++) {
          f32x4 a = {};
#pragma unroll
          for (int s = 0; s < 2; s++) {
            bf16x8 bk = *reinterpret_cast<const bf16x8*>(
                &Klds[half * 64 + nt * 16 + mlane][((4 * s + quad) ^ m7) * 8]);
            a = __builtin_amdgcn_mfma_f32_16x16x32_bf16(bk, qf[s], a, 0, 0, 0);
          }
          sc[nt] = a;
        }
        __builtin_amdgcn_s_setprio(0);

        // issue V fragment loads early: latency hides under softmax + pack
        bf16x8 vfr[2][4];
#pragma unroll
        for (int s = 0; s < 2; s++)
#pragma unroll
          for (int nt = 0; nt < 4; nt++)
            vfr[s][nt] = *reinterpret_cast<const bf16x8*>(
                vb + (size_t)nt * 16 * S + kb * 128 + s * 32);

        const bool maskTile = (kb == nkb - 1);
#pragma unroll
        for (int nt = 0; nt < 4; nt++) {
          if (maskTile) {
            const int kg0 = kb * 128 + half * 64 + nt * 16 + quad * 4;
#pragma unroll
            for (int r = 0; r < 4; r++)
              if (kg0 + r > qg) sc[nt][r] = -INFINITY;
          }
#pragma unroll
          for (int r = 0; r < 4; r++) {
            float p = __builtin_amdgcn_exp2f(sc[nt][r]);
            sc[nt][r] = p;
            lsum += p;
          }
        }

        unsigned w00 = pk2(sc[0][0], sc[0][1]), w01 = pk2(sc[0][2], sc[0][3]);
        unsigned w10 = pk2(sc[1][0], sc[1][1]), w11 = pk2(sc[1][2], sc[1][3]);
        unsigned w20 = pk2(sc[2][0], sc[2][1]), w21 = pk2(sc[2][2], sc[2][3]);
        unsigned w30 = pk2(sc[3][0], sc[3][1]), w31 = pk2(sc[3][2], sc[3][3]);

        u32x2 t0 = __builtin_amdgcn_permlane32_swap(w00, w10, false, false);
        u32x2 z02 = __builtin_amdgcn_permlane16_swap(t0.x, t0.y, false, false);
        u32x2 t1 = __builtin_amdgcn_permlane32_swap(w01, w11, false, false);
        u32x2 z13 = __builtin_amdgcn_permlane16_swap(t1.x, t1.y, false, false);
        u32x2 t2 = __builtin_amdgcn_permlane32_swap(w20, w30, false, false);
        u32x2 z02b = __builtin_amdgcn_permlane16_swap(t2.x, t2.y, false, false);
        u32x2 t3 = __builtin_amdgcn_permlane32_swap(w21, w31, false, false);
        u32x2 z13b = __builtin_amdgcn_permlane16_swap(t3.x, t3.y, false, false);
        u32x4 pf0u = {z02.x, z13.x, z02.y, z13.y};
        u32x4 pf1u = {z02b.x, z13b.x, z02b.y, z13b.y};
        bf16x8 pf[2] = {__builtin_bit_cast(bf16x8, pf0u),
                        __builtin_bit_cast(bf16x8, pf1u)};

        __builtin_amdgcn_s_setprio(1);
#pragma unroll
        for (int s = 0; s < 2; s++)
#pragma unroll
          for (int nt = 0; nt < 4; nt++)
            o[nt] = __builtin_amdgcn_mfma_f32_16x16x32_bf16(pf[s], vfr[s][nt], o[nt],
                                                            0, 0, 0);
        __builtin_amdgcn_s_setprio(0);
      }
      __syncthreads();
    }

    lsum += __shfl_xor(lsum, 16, 64);
    lsum += __shfl_xor(lsum, 32, 64);

    // merge key-halves; scratch overlays K region (all K reads are done)
    float* osc = (float*)smem;            // [rw][lane][17]  17408 B
    float* lsc = (float*)(smem + 17408);  // [2][4][16]      512 B
    if (lane < 16) lsc[half * 64 + rw * 16 + lane] = lsum;
    if (half == 1) {
      const int ob = (rw * 64 + lane) * 17;
#pragma unroll
      for (int nt = 0; nt < 4; nt++)
#pragma unroll
        for (int r = 0; r < 4; r++) osc[ob + nt * 4 + r] = o[nt][r];
    }
    __syncthreads();
    if (half == 0) {
      const int ob = (rw * 64 + lane) * 17;
#pragma unroll
      for (int nt = 0; nt < 4; nt++)
#pragma unroll
        for (int r = 0; r < 4; r++) o[nt][r] += osc[ob + nt * 4 + r];
#pragma unroll
      for (int r = 0; r < 4; r++) {
        float l = lsc[rw * 16 + quad * 4 + r] + lsc[64 + rw * 16 + quad * 4 + r];
        float inv = 1.0f / l;
        int row = qbase + quad * 4 + r;
#pragma unroll
        for (int nt = 0; nt < 4; nt++)
          O[(size_t)row * D + h * 64 + nt * 16 + mlane] = (__bf16)(o[nt][r] * inv);
      }
    }
    __syncthreads();
  }
}

extern "C" void kernel_launch(void* const* d_in, const int* in_sizes, int n_in,
                              void* d_out, int out_size, void* d_ws, size_t ws_size,
                              hipStream_t stream) {
  const float* query = (const float*)d_in[0];
  const float* Wq = (const float*)d_in[2];
  const float* bq = (const float*)d_in[3];
  const float* Wk = (const float*)d_in[4];
  const float* bk = (const float*)d_in[5];
  const float* Wv = (const float*)d_in[6];
  const float* bv = (const float*)d_in[7];
  const float* Wo = (const float*)d_in[8];
  const float* bo = (const float*)d_in[9];
  float* out = (float*)d_out;

  const int S = 4096, D = 1024;
  const float SCL = 0.125f * 1.44269504088896340736f;
  char* ws = (char*)d_ws;
  __bf16* Xb   = (__bf16*)(ws);
  __bf16* Cb   = (__bf16*)(ws);
  __bf16* Wqkv = (__bf16*)(ws + (8u << 20));
  __bf16* Wob  = (__bf16*)(ws + (14u << 20));
  __bf16* QKb  = (__bf16*)(ws + (16u << 20));
  __bf16* Vt   = (__bf16*)(ws + (32u << 20));

  cast_all<<<dim3(512, 5), 256, 0, stream>>>(query, Wq, Wk, Wv, Wo, Xb, Wqkv, Wob, SCL);

  // QKV projection: 8-phase 256^2 pipeline; V region written transposed into Vt
  gemm8p<<<dim3(S / 256, 3 * D / 256), 512, 0, stream>>>(
      Xb, Wqkv, bq, bk, bv, QKb, Vt, D, 2048, SCL);

  // balanced split-key causal flash attention (V read from L2, K-only LDS)
  flash_attn<<<dim3(32, 16), 512, 0, stream>>>(QKb, Vt, Cb, S);

  // output projection (fp32 out)
  gemm_bt<64, float><<<dim3(S / 64, D / 128), 512, 0, stream>>>(
      Cb, Wob, bo, out, D, D);
}